// Round 13
// baseline (236.208 us; speedup 1.0000x reference)
//
#include <hip/hip_runtime.h>

#define NB   256            // z-buckets
#define ZMIN -4.5f
#define ZSPAN 9.0f
#define BW   (ZSPAN / (float)NB)
#define K1T  64             // build-kernel threads
#define TPB  256            // search block

__device__ __forceinline__ int zbucket(float z) {
    int b = (int)((z - ZMIN) * ((float)NB / ZSPAN));
    return b < 0 ? 0 : (b > NB - 1 ? NB - 1 : b);
}

// ---- K1: deterministic counting sort by z-bucket (per set,batch) ----
// Stable two-level rank: per-thread span hist -> cross-span prefix per bucket
// -> sequential scatter. No atomics: bitwise deterministic.
__global__ void __launch_bounds__(K1T) build(const float* __restrict__ preds,
                                             const float* __restrict__ gts,
                                             float4* __restrict__ SP, int* __restrict__ IP,
                                             float4* __restrict__ SG, int* __restrict__ IG,
                                             int* __restrict__ bs,   // [2][B][NB+1]
                                             int N, int M, int B) {
    const int set   = blockIdx.x / B;
    const int batch = blockIdx.x - set * B;
    const int n = set ? M : N;
    const float* __restrict__ src = set ? gts + (size_t)batch * M * 3
                                        : preds + (size_t)batch * N * 3;
    float4* __restrict__ dstS = set ? SG + (size_t)batch * M : SP + (size_t)batch * N;
    int*    __restrict__ dstI = set ? IG + (size_t)batch * M : IP + (size_t)batch * N;
    int*    __restrict__ bsRow = bs + ((size_t)set * B + batch) * (NB + 1);

    __shared__ unsigned short hist[K1T][NB];   // 32 KB (counts/prefix <= 8192)
    __shared__ int btot[NB];
    __shared__ int bstart[NB + 1];

    const int t   = (int)threadIdx.x;
    const int npt = (n + K1T - 1) / K1T;

    for (int idx = t; idx < K1T * NB; idx += K1T) ((unsigned short*)hist)[idx] = 0;
    __syncthreads();

    // A: per-span histogram (sequential per thread)
    for (int j = 0; j < npt; ++j) {
        int p = t * npt + j;
        if (p < n) hist[t][zbucket(src[3 * p + 2])]++;
    }
    __syncthreads();

    // B: per bucket, exclusive prefix across spans; bucket totals
    for (int b = t; b < NB; b += K1T) {
        int run = 0;
        for (int s = 0; s < K1T; ++s) {
            int v = hist[s][b];
            hist[s][b] = (unsigned short)run;
            run += v;
        }
        btot[b] = run;
    }
    __syncthreads();

    // C: bucket starts (serial scan), publish
    if (t == 0) {
        int acc = 0;
        for (int b = 0; b < NB; ++b) { bstart[b] = acc; acc += btot[b]; }
        bstart[NB] = acc;
    }
    __syncthreads();
    for (int b = t; b <= NB; b += K1T) bsRow[b] = bstart[b];

    // D: stable scatter (sequential per thread), pack {x,y,z,||.||^2}+origIdx
    for (int j = 0; j < npt; ++j) {
        int p = t * npt + j;
        if (p < n) {
            float x = src[3 * p], y = src[3 * p + 1], z = src[3 * p + 2];
            int b = zbucket(z);
            int pos = bstart[b] + (int)hist[t][b];
            hist[t][b]++;
            dstS[pos] = make_float4(x, y, z, fmaf(x, x, fmaf(y, y, z * z)));
            dstI[pos] = p;
        }
    }
}

// ---- K2: pruned NN search. One thread = one query (sorted order -> wave-
// coherent buckets). Shell expansion with per-lane exact bound (TRUE distance^2
// = partial-min + ||q||^2 — round-12 bug was comparing against the partial),
// wave-uniform exit. Refs wave-uniform -> broadcast loads; 16-chunk. ----
#define EVAL(rr, mm) mm = fminf(mm, fmaf(q2x, (rr).x, fmaf(q2y, (rr).y, fmaf(q2z, (rr).z, (rr).w))));

__global__ void __launch_bounds__(TPB) search(const float4* __restrict__ SP,
                                              const float4* __restrict__ SG,
                                              const int* __restrict__ IP,
                                              const int* __restrict__ IG,
                                              const int* __restrict__ bs,
                                              float* __restrict__ fmP,
                                              float* __restrict__ fmG,
                                              int N, int M, int B) {
    const int set   = blockIdx.z;
    const int batch = blockIdx.y;
    const int nQ = set ? M : N;
    const float4* __restrict__ Q  = set ? SG + (size_t)batch * M : SP + (size_t)batch * N;
    const int*    __restrict__ QI = set ? IG + (size_t)batch * M : IP + (size_t)batch * N;
    const float4* __restrict__ R  = set ? SP + (size_t)batch * N : SG + (size_t)batch * M;
    const int*    __restrict__ tb = bs + ((size_t)(1 - set) * B + batch) * (NB + 1);
    float*        __restrict__ fm = set ? fmG + (size_t)batch * M : fmP + (size_t)batch * N;

    const int qpos = blockIdx.x * TPB + (int)threadIdx.x;
    const int qc   = qpos < nQ ? qpos : nQ - 1;
    const float4 q = Q[qc];
    const float q2x = -2.f * q.x, q2y = -2.f * q.y, q2z = -2.f * q.z;

    float m0 = 3.4e38f, m1 = 3.4e38f;

    auto scan = [&](int lo, int hi) {
        int i = lo;
        for (; i + 16 <= hi; i += 16) {
            float4 a0 = R[i+0],  a1 = R[i+1],  a2 = R[i+2],  a3 = R[i+3];
            float4 a4 = R[i+4],  a5 = R[i+5],  a6 = R[i+6],  a7 = R[i+7];
            float4 a8 = R[i+8],  a9 = R[i+9],  a10 = R[i+10], a11 = R[i+11];
            float4 a12 = R[i+12], a13 = R[i+13], a14 = R[i+14], a15 = R[i+15];
            EVAL(a0, m0)  EVAL(a1, m1)  EVAL(a2, m0)  EVAL(a3, m1)
            EVAL(a4, m0)  EVAL(a5, m1)  EVAL(a6, m0)  EVAL(a7, m1)
            EVAL(a8, m0)  EVAL(a9, m1)  EVAL(a10, m0) EVAL(a11, m1)
            EVAL(a12, m0) EVAL(a13, m1) EVAL(a14, m0) EVAL(a15, m1)
        }
        for (; i + 4 <= hi; i += 4) {
            float4 a0 = R[i], a1 = R[i+1], a2 = R[i+2], a3 = R[i+3];
            EVAL(a0, m0) EVAL(a1, m1) EVAL(a2, m0) EVAL(a3, m1)
        }
        for (; i < hi; ++i) { float4 a = R[i]; EVAL(a, m0) }
    };

    const int bq   = zbucket(q.z);
    const int bmin = __builtin_amdgcn_readfirstlane(bq);              // lane 0 (sorted)
    const int bmax = __builtin_amdgcn_readfirstlane(__shfl(bq, 63));  // lane 63
    auto TB = [&](int b) { return __builtin_amdgcn_readfirstlane(tb[b]); };

    scan(TB(bmin), TB(bmax + 1));   // own bucket range first

    int bl = bmin - 1, br = bmax + 1;
    bool goL = bl >= 0, goR = br < NB;
    while (goL || goR) {
        const float mt = fminf(m0, m1) + q.w;   // TRUE best distance^2 so far
        if (goL) {
            float gl = q.z - (ZMIN + (float)(bl + 1) * BW);   // gap to bucket's near edge
            bool need = gl * gl * 0.999f < mt;
            if (__any(need)) { scan(TB(bl), TB(bl + 1)); --bl; goL = bl >= 0; }
            else goL = false;
        }
        if (goR) {
            float gr = (ZMIN + (float)br * BW) - q.z;
            bool need = gr * gr * 0.999f < mt;
            if (__any(need)) { scan(TB(br), TB(br + 1)); ++br; goR = br < NB; }
            else goR = false;
        }
    }

    if (qpos < nQ) fm[QI[qc]] = fminf(m0, m1) + q.w;   // one writer/query
}
#undef EVAL

// ---- K3: fixed-order sums per batch ----
__global__ void __launch_bounds__(256) finish(const float* __restrict__ fmP,
                                              const float* __restrict__ fmG,
                                              float* __restrict__ out,
                                              int N, int M, int B) {
    const int b = blockIdx.x;
    const float* r0 = fmP + (size_t)b * N;
    const float* r1 = fmG + (size_t)b * M;

    float s0 = 0.f, s1 = 0.f;
    for (int i = (int)threadIdx.x; i < N; i += 256) s0 += r0[i];
    for (int i = (int)threadIdx.x; i < M; i += 256) s1 += r1[i];

    for (int off = 32; off > 0; off >>= 1) {
        s0 += __shfl_down(s0, off);
        s1 += __shfl_down(s1, off);
    }
    __shared__ float w0[4], w1[4];
    const int wid = (int)threadIdx.x >> 6, lane = (int)threadIdx.x & 63;
    if (lane == 0) { w0[wid] = s0; w1[wid] = s1; }
    __syncthreads();
    if (threadIdx.x == 0) {
        float S0 = 0.f, S1 = 0.f;
        #pragma unroll
        for (int w = 0; w < 4; ++w) { S0 += w0[w]; S1 += w1[w]; }
        out[b] = S0 / (float)N + S1 / (float)M;
    }
}

extern "C" void kernel_launch(void* const* d_in, const int* in_sizes, int n_in,
                              void* d_out, int out_size, void* d_ws, size_t ws_size,
                              hipStream_t stream) {
    const float* preds = (const float*)d_in[0];  // [B, N, 3]
    const float* gts   = (const float*)d_in[1];  // [B, M, 3]
    float* out = (float*)d_out;                  // [B]

    const int B = out_size;                      // 8
    const int N = in_sizes[0] / (B * 3);         // 8192
    const int M = in_sizes[1] / (B * 3);         // 8192

    float4* SP  = (float4*)d_ws;                 // [B*N] sorted preds {x,y,z,w}
    float4* SG  = SP + (size_t)B * N;            // [B*M] sorted gts
    int*    IP  = (int*)(SG + (size_t)B * M);    // [B*N] orig idx
    int*    IG  = IP + (size_t)B * N;            // [B*M]
    int*    bsT = IG + (size_t)B * M;            // [2][B][NB+1]
    float*  fmP = (float*)(bsT + (size_t)2 * B * (NB + 1));  // [B*N] per-pred min
    float*  fmG = fmP + (size_t)B * N;                       // [B*M] per-gt  min

    build<<<2 * B, K1T, 0, stream>>>(preds, gts, SP, IP, SG, IG, bsT, N, M, B);

    const int nMax = N > M ? N : M;
    dim3 grid((nMax + TPB - 1) / TPB, B, 2);     // (32, 8, 2) = 512 blocks
    search<<<grid, TPB, 0, stream>>>(SP, SG, IP, IG, bsT, fmP, fmG, N, M, B);

    finish<<<B, 256, 0, stream>>>(fmP, fmG, out, N, M, B);
}

// Round 15
// 234.285 us; speedup vs baseline: 1.0082x; 1.0082x over previous
//
#include <hip/hip_runtime.h>

#define NB   256            // z-buckets
#define ZMIN -4.5f
#define ZSPAN 9.0f
#define BW   (ZSPAN / (float)NB)
#define TPB  256
#define QL   4              // lanes per query (quad)

__device__ __forceinline__ int zbucket(float z) {
    int b = (int)((z - ZMIN) * ((float)NB / ZSPAN));
    return b < 0 ? 0 : (b > NB - 1 ? NB - 1 : b);
}

// ---------------- build: count -> prefix -> scatter (atomic, wide) ----------
// Intra-bucket order is nondeterministic BUT the final output is bit-exact
// deterministic: per-query min is a lattice op over the same candidate SET
// (fminf has no rounding; bucket-skip decisions happen at bucket granularity
// over completed-bucket sets, so the scanned set is replay-invariant), one
// writer per query, and the final sum runs in fixed original-index order.

__global__ void __launch_bounds__(TPB) count_pts(const float* __restrict__ preds,
                                                 const float* __restrict__ gts,
                                                 int* __restrict__ counts,  // [2*B][NB]
                                                 int N, int M, int B) {
    int id = blockIdx.x * TPB + threadIdx.x;
    const int totP = B * N;
    if (id < totP) {
        int batch = id / N;
        float z = preds[3 * (size_t)id + 2];
        atomicAdd(&counts[(size_t)batch * NB + zbucket(z)], 1);
    } else if (id < totP + B * M) {
        int k = id - totP;
        int batch = k / M;
        float z = gts[3 * (size_t)k + 2];
        atomicAdd(&counts[(size_t)(B + batch) * NB + zbucket(z)], 1);
    }
}

// One block per (set,batch) row: thread 0 serial-scans 256 entries (micro work).
__global__ void __launch_bounds__(64) prefix_row(const int* __restrict__ counts,
                                                 int* __restrict__ bs,      // [2*B][NB+1]
                                                 int* __restrict__ cursor)  // [2*B][NB]
{
    const int row = blockIdx.x;
    if (threadIdx.x == 0) {
        const int* c = counts + (size_t)row * NB;
        int* b = bs + (size_t)row * (NB + 1);
        int* u = cursor + (size_t)row * NB;
        int acc = 0;
        for (int i = 0; i < NB; ++i) { b[i] = acc; u[i] = acc; acc += c[i]; }
        b[NB] = acc;
    }
}

__global__ void __launch_bounds__(TPB) scatter_pts(const float* __restrict__ preds,
                                                   const float* __restrict__ gts,
                                                   float4* __restrict__ SP, int* __restrict__ IP,
                                                   float4* __restrict__ SG, int* __restrict__ IG,
                                                   int* __restrict__ cursor,
                                                   int N, int M, int B) {
    int id = blockIdx.x * TPB + threadIdx.x;
    const int totP = B * N;
    if (id < totP) {
        int batch = id / N, p = id - batch * N;
        float x = preds[3 * (size_t)id], y = preds[3 * (size_t)id + 1], z = preds[3 * (size_t)id + 2];
        int pos = atomicAdd(&cursor[(size_t)batch * NB + zbucket(z)], 1);
        SP[(size_t)batch * N + pos] = make_float4(x, y, z, fmaf(x, x, fmaf(y, y, z * z)));
        IP[(size_t)batch * N + pos] = p;
    } else if (id < totP + B * M) {
        int k = id - totP;
        int batch = k / M, p = k - batch * M;
        float x = gts[3 * (size_t)k], y = gts[3 * (size_t)k + 1], z = gts[3 * (size_t)k + 2];
        int pos = atomicAdd(&cursor[(size_t)(B + batch) * NB + zbucket(z)], 1);
        SG[(size_t)batch * M + pos] = make_float4(x, y, z, fmaf(x, x, fmaf(y, y, z * z)));
        IG[(size_t)batch * M + pos] = p;
    }
}

// ---------------- search: 4 lanes per query, per-quad shell expansion -------
#define EVAL(rr, mm) mm = fminf(mm, fmaf(q2x, (rr).x, fmaf(q2y, (rr).y, fmaf(q2z, (rr).z, (rr).w))));

__global__ void __launch_bounds__(TPB) search(const float4* __restrict__ SP,
                                              const float4* __restrict__ SG,
                                              const int* __restrict__ IP,
                                              const int* __restrict__ IG,
                                              const int* __restrict__ bs,
                                              float* __restrict__ fmP,
                                              float* __restrict__ fmG,
                                              int N, int M, int B) {
    const int set   = blockIdx.z;
    const int batch = blockIdx.y;
    const int nQ = set ? M : N;
    const float4* __restrict__ Q  = set ? SG + (size_t)batch * M : SP + (size_t)batch * N;
    const int*    __restrict__ QI = set ? IG + (size_t)batch * M : IP + (size_t)batch * N;
    const float4* __restrict__ R  = set ? SP + (size_t)batch * N : SG + (size_t)batch * M;
    const int*    __restrict__ tb = bs + ((size_t)((1 - set) * B + batch)) * (NB + 1);
    float*        __restrict__ fm = set ? fmG + (size_t)batch * M : fmP + (size_t)batch * N;

    const int gtid = blockIdx.x * TPB + (int)threadIdx.x;
    const int qpos = gtid >> 2;          // query index (4 lanes each)
    const int ql   = gtid & (QL - 1);
    const int qc   = qpos < nQ ? qpos : nQ - 1;
    const float4 q = Q[qc];
    const float q2x = -2.f * q.x, q2y = -2.f * q.y, q2z = -2.f * q.z;

    float m0 = 3.4e38f, m1 = 3.4e38f;

    // Quad-strided scan of [lo,hi): lane ql covers lo+ql, lo+ql+QL, ...
    auto scan = [&](int lo, int hi) {
        int i = lo + ql;
        for (; i + 3 * QL < hi; i += 4 * QL) {
            float4 a0 = R[i], a1 = R[i + QL], a2 = R[i + 2 * QL], a3 = R[i + 3 * QL];
            EVAL(a0, m0) EVAL(a1, m1) EVAL(a2, m0) EVAL(a3, m1)
        }
        for (; i < hi; i += QL) { float4 a = R[i]; EVAL(a, m0) }
    };
    // Quad-combined running min (2 shuffles; quad-uniform result).
    // MUST be called with all 4 quad lanes active (shfl reads lane registers
    // regardless of exec — calling it under a ql==0 guard reads stale regs).
    auto qmin = [&]() {
        float v = fminf(m0, m1);
        v = fminf(v, __shfl_xor(v, 1));
        v = fminf(v, __shfl_xor(v, 2));
        return v;
    };

    const int bq = zbucket(q.z);
    scan(tb[bq], tb[bq + 1]);            // own bucket first

    int bl = bq - 1, br = bq + 1;
    bool goL = bl >= 0, goR = br < NB;
    while (goL || goR) {
        const float mt = qmin() + q.w;   // TRUE best distance^2 so far (quad-uniform)
        if (goL) {
            float gl = q.z - (ZMIN + (float)(bl + 1) * BW);
            if (gl * gl * 0.999f < mt) { scan(tb[bl], tb[bl + 1]); --bl; goL = bl >= 0; }
            else goL = false;
        }
        if (goR) {
            float gr = (ZMIN + (float)br * BW) - q.z;
            if (gr * gr * 0.999f < mt) { scan(tb[br], tb[br + 1]); ++br; goR = br < NB; }
            else goR = false;
        }
    }

    // Round-14 bug fix: reduce with ALL lanes active, THEN the lane-0 write.
    const float res = qmin() + q.w;
    if (ql == 0 && qpos < nQ) fm[QI[qc]] = res;   // one writer/query
}
#undef EVAL

// ---------------- finish: fixed-order sums per batch ------------------------
__global__ void __launch_bounds__(256) finish(const float* __restrict__ fmP,
                                              const float* __restrict__ fmG,
                                              float* __restrict__ out,
                                              int N, int M, int B) {
    const int b = blockIdx.x;
    const float* r0 = fmP + (size_t)b * N;
    const float* r1 = fmG + (size_t)b * M;

    float s0 = 0.f, s1 = 0.f;
    for (int i = (int)threadIdx.x; i < N; i += 256) s0 += r0[i];
    for (int i = (int)threadIdx.x; i < M; i += 256) s1 += r1[i];

    for (int off = 32; off > 0; off >>= 1) {
        s0 += __shfl_down(s0, off);
        s1 += __shfl_down(s1, off);
    }
    __shared__ float w0[4], w1[4];
    const int wid = (int)threadIdx.x >> 6, lane = (int)threadIdx.x & 63;
    if (lane == 0) { w0[wid] = s0; w1[wid] = s1; }
    __syncthreads();
    if (threadIdx.x == 0) {
        float S0 = 0.f, S1 = 0.f;
        #pragma unroll
        for (int w = 0; w < 4; ++w) { S0 += w0[w]; S1 += w1[w]; }
        out[b] = S0 / (float)N + S1 / (float)M;
    }
}

extern "C" void kernel_launch(void* const* d_in, const int* in_sizes, int n_in,
                              void* d_out, int out_size, void* d_ws, size_t ws_size,
                              hipStream_t stream) {
    const float* preds = (const float*)d_in[0];  // [B, N, 3]
    const float* gts   = (const float*)d_in[1];  // [B, M, 3]
    float* out = (float*)d_out;                  // [B]

    const int B = out_size;                      // 8
    const int N = in_sizes[0] / (B * 3);         // 8192
    const int M = in_sizes[1] / (B * 3);         // 8192

    float4* SP     = (float4*)d_ws;                        // [B*N] sorted preds
    float4* SG     = SP + (size_t)B * N;                   // [B*M] sorted gts
    int*    IP     = (int*)(SG + (size_t)B * M);           // [B*N] orig idx
    int*    IG     = IP + (size_t)B * N;                   // [B*M]
    int*    bsT    = IG + (size_t)B * M;                   // [2*B][NB+1]
    int*    cursor = bsT + (size_t)2 * B * (NB + 1);       // [2*B][NB]
    int*    counts = cursor + (size_t)2 * B * NB;          // [2*B][NB]
    float*  fmP    = (float*)(counts + (size_t)2 * B * NB);// [B*N]
    float*  fmG    = fmP + (size_t)B * N;                  // [B*M]

    const int total = B * (N + M);
    hipMemsetAsync(counts, 0, (size_t)2 * B * NB * sizeof(int), stream);
    count_pts<<<(total + TPB - 1) / TPB, TPB, 0, stream>>>(preds, gts, counts, N, M, B);
    prefix_row<<<2 * B, 64, 0, stream>>>(counts, bsT, cursor);
    scatter_pts<<<(total + TPB - 1) / TPB, TPB, 0, stream>>>(preds, gts, SP, IP, SG, IG,
                                                             cursor, N, M, B);

    const int nMax = N > M ? N : M;
    dim3 grid((nMax * QL + TPB - 1) / TPB, B, 2);   // (128, 8, 2) = 2048 blocks
    search<<<grid, TPB, 0, stream>>>(SP, SG, IP, IG, bsT, fmP, fmG, N, M, B);

    finish<<<B, 256, 0, stream>>>(fmP, fmG, out, N, M, B);
}